// Round 8
// baseline (183.822 us; speedup 1.0000x reference)
//
#include <hip/hip_runtime.h>

#define LROW 136   // padded LDS row stride in bf16 elements (128 + 8); 272 B rows
#define FSTR 72    // feat row stride in bf16 (64 K-cols + 8 pad); 144 B rows

typedef __bf16 bf16x8  __attribute__((ext_vector_type(8)));
typedef float  f32x4   __attribute__((ext_vector_type(4)));
typedef float  f32x2   __attribute__((ext_vector_type(2)));

#define MFMA16(a, b, c) __builtin_amdgcn_mfma_f32_16x16x32_bf16((a), (b), (c), 0, 0, 0)

__device__ __forceinline__ float bflo(unsigned v) { return __uint_as_float(v << 16); }
__device__ __forceinline__ float bfhi(unsigned v) { return __uint_as_float(v & 0xffff0000u); }

__device__ __forceinline__ unsigned short f2bf_u16(float f) {
  unsigned u = __float_as_uint(f);
  u += 0x7fffu + ((u >> 16) & 1u);
  return (unsigned short)(u >> 16);
}

// ---------------------------------------------------------------------------
// Kernel 1: fold linear layers into combined weight matrices (bf16, [n][k]
// transposed layout) + folded bias vectors (f32) + W1pT (pre_W1 transposed,
// bias folded as feature k=42, zero-padded to K=64).
// ---------------------------------------------------------------------------
__global__ void combine_weights(
    const float* __restrict__ pre_W1, const float* __restrict__ pre_b1,
    const float* __restrict__ pre_W2, const float* __restrict__ msg_W1,
    const float* __restrict__ msg_W2, const float* __restrict__ post_W1,
    const float* __restrict__ post_W2, const float* __restrict__ out_W1,
    const float* __restrict__ out_W2, const float* __restrict__ pre_b2,
    const float* __restrict__ msg_b1, const float* __restrict__ msg_b2,
    const float* __restrict__ post_b1, const float* __restrict__ post_b2,
    const float* __restrict__ out_b1,
    unsigned short* __restrict__ WabT, unsigned short* __restrict__ WdT,
    unsigned short* __restrict__ WcT, unsigned short* __restrict__ WoT,
    unsigned short* __restrict__ Wo2T, unsigned short* __restrict__ W1pT,
    float* __restrict__ vecs)
{
  __shared__ float part[256];
  const int b = blockIdx.x;
  const int t = threadIdx.x;
  if (b < 320) {
    const int p  = b >> 6;
    const int kp = b & 63;
    const int k  = kp * 2 + (t >> 7);
    const int n  = t & 127;
    const float* L; const float* R; unsigned short* O;
    if (p == 0)      { L = pre_W2;  R = msg_W1;             O = WabT; }
    else if (p == 1) { L = pre_W2;  R = msg_W1 + 128*128;   O = WabT + 128*128; }
    else if (p == 2) { L = pre_W2;  R = post_W1 + 128*128;  O = WdT; }
    else if (p == 3) { L = msg_W2;  R = post_W1;            O = WcT; }
    else             { L = post_W2; R = out_W1;             O = WoT; }
    const float* Lr = L + k * 128;
    float a0 = 0.f, a1 = 0.f, a2 = 0.f, a3 = 0.f;
    #pragma unroll 8
    for (int m = 0; m < 128; m += 4) {
      a0 = fmaf(Lr[m + 0], R[(m + 0) * 128 + n], a0);
      a1 = fmaf(Lr[m + 1], R[(m + 1) * 128 + n], a1);
      a2 = fmaf(Lr[m + 2], R[(m + 2) * 128 + n], a2);
      a3 = fmaf(Lr[m + 3], R[(m + 3) * 128 + n], a3);
    }
    O[n * 128 + k] = f2bf_u16((a0 + a1) + (a2 + a3));
  } else if (b == 320) {
    // Wo2T transpose, w1d copy, W1pT build
    for (int idx = t; idx < 16 * 128; idx += 256) {
      int o = idx >> 7, k = idx & 127;
      Wo2T[o * 128 + k] = f2bf_u16(out_W2[k * 16 + o]);
    }
    if (t < 128) vecs[t] = msg_W1[256 * 128 + t];          // w1d
    for (int idx = t; idx < 128 * 64; idx += 256) {
      int n = idx >> 6, k = idx & 63;
      float v = (k < 42) ? pre_W1[k * 128 + n] : (k == 42 ? pre_b1[n] : 0.f);
      W1pT[n * 64 + k] = f2bf_u16(v);
    }
  } else {
    const int n = t & 127;
    const int h = t >> 7;
    float s = 0.f;
    if (b == 321) {            // cAB = pre_b2@(W1a+W1b) + msg_b1
      #pragma unroll 8
      for (int m = h * 64; m < h * 64 + 64; ++m)
        s = fmaf(pre_b2[m], msg_W1[m * 128 + n] + msg_W1[(128 + m) * 128 + n], s);
    } else if (b == 322) {     // cP = 7*msg_b2@P1a + pre_b2@P1b + post_b1
      #pragma unroll 8
      for (int m = h * 64; m < h * 64 + 64; ++m) {
        s = fmaf(7.f * msg_b2[m], post_W1[m * 128 + n], s);
        s = fmaf(pre_b2[m], post_W1[(128 + m) * 128 + n], s);
      }
    } else {                   // cO = 8*post_b2@out_W1 + out_b1
      #pragma unroll 8
      for (int m = h * 64; m < h * 64 + 64; ++m)
        s = fmaf(8.f * post_b2[m], out_W1[m * 128 + n], s);
    }
    part[t] = s;
    __syncthreads();
    if (t < 128) {
      float r = part[t] + part[t + 128];
      if (b == 321)      vecs[128 + t] = r + msg_b1[t];
      else if (b == 322) vecs[256 + t] = r + post_b1[t];
      else               vecs[384 + t] = r + out_b1[t];
    }
  }
}

// ---------------------------------------------------------------------------
// Kernel 2: fully fused RRN. R8: same 8-graph/64-row tile as R7 (smaller
// tiles regress: per-block fixed cost + weight L2 re-fetch), but 512 threads
// = 8 waves/block. Each wave owns a 32-row half x 32-col quarter -> acc peak
// 8 accs (32 regs), combined regfile ~75 -> __launch_bounds__(512,6) gives
// 3 blocks/CU = 24 waves/CU (75% cap, was 50%). Same block count, same
// weight traffic, 2x resident waves to hide barrier drains.
// ---------------------------------------------------------------------------
__global__ void __launch_bounds__(512, 6) rrn_main(
    const int* __restrict__ anchors, const int* __restrict__ n_jumps,
    const float* __restrict__ positions, const int* __restrict__ colors,
    const int* __restrict__ markers,
    const __bf16* __restrict__ W1pT,
    const __bf16* __restrict__ WabT, const __bf16* __restrict__ WdT,
    const __bf16* __restrict__ WcT, const __bf16* __restrict__ WoT,
    const __bf16* __restrict__ Wo2T, const float* __restrict__ vecs,
    const float* __restrict__ out_b2, float* __restrict__ out)
{
  __shared__ __align__(16) char smem[38912];
  // X [0,17408): phases 0-1: featL bf16[64][FSTR] (9216 B). Phase 2+: Ab
  //   bf16[64][LROW] (A, then S in place).
  // Y [17408,34816): h1 bf16[64][LROW] (phases 1-2); Bb after D pass;
  //   Sph @17408 / hob @21760 (phases 5+).
  // dist f32[512] @34816; vec f32[512] @36864.
  __bf16* featL = (__bf16*)(smem);
  __bf16* Ab    = (__bf16*)(smem);
  __bf16* h1    = (__bf16*)(smem + 17408);
  __bf16* Bb    = (__bf16*)(smem + 17408);
  __bf16* Sph   = (__bf16*)(smem + 17408);
  __bf16* hob   = (__bf16*)(smem + 21760);
  float*  dist  = (float*)(smem + 34816);
  float*  vec   = (float*)(smem + 36864);

  const int tid  = threadIdx.x;
  const int lane = tid & 63;
  const int w    = tid >> 6;      // wave 0..7
  const int l15  = lane & 15;
  const int quad = lane >> 4;
  const int rh   = w & 1;         // row half: rows rh*32 .. rh*32+31
  const int rowh = rh * 32;
  const int colq = (w >> 1) * 32; // col quarter: cols colq .. colq+31
  const int g0   = blockIdx.x * 8;
  const int n0   = blockIdx.x * 64;

  // ---- phase 0: build feature rows (thread-private: no race), dist, vec
  if (tid < 64) {
    uint4* rp = (uint4*)&featL[tid * FSTR];   // 144 B row, 16B-aligned
    uint4 z4 = {0u, 0u, 0u, 0u};
    #pragma unroll
    for (int i = 0; i < 9; ++i) rp[i] = z4;
    int g = tid >> 3;
    float px = positions[(n0 + tid) * 2], py = positions[(n0 + tid) * 2 + 1];
    int c  = colors[n0 + tid], mk = markers[n0 + tid] - 8;
    int a  = anchors[g0 + g],  nj = n_jumps[g0 + g];
    __bf16* row = &featL[tid * FSTR];
    row[0] = (__bf16)px; row[1] = (__bf16)py;
    const __bf16 one = (__bf16)1.f;
    row[2 + c] = one; row[10 + mk] = one;
    row[18 + a] = one; row[34 + nj] = one;
    row[42] = one;                              // bias-as-feature
  }
  {
    int i = tid;                                // 512 threads cover 512 edges
    int g = i >> 6, ii = (i >> 3) & 7, jj = i & 7;
    const float* pa = positions + (n0 + g * 8 + ii) * 2;
    const float* pb = positions + (n0 + g * 8 + jj) * 2;
    float dx = pa[0] - pb[0], dy = pa[1] - pb[1];
    dist[i] = sqrtf(dx * dx + dy * dy);
  }
  vec[tid] = vecs[tid];
  __syncthreads();

  // ---- phase 1: h1 = relu(featL @ W1pT) via MFMA (M=64, N=128, K=64 padded)
  //      Wave: rows rowh..+31 (mt 0,1), cols colq..+31 (nt 0,1).
  {
    f32x4 acch[2][2];
    f32x4 zero = {0.f, 0.f, 0.f, 0.f};
    acch[0][0] = zero; acch[0][1] = zero; acch[1][0] = zero; acch[1][1] = zero;
    #pragma unroll
    for (int kb = 0; kb < 64; kb += 32) {
      const int ko = kb + quad * 8;
      bf16x8 fa[2], fb[2];
      fa[0] = *(const bf16x8*)&featL[(rowh + l15) * FSTR + ko];
      fa[1] = *(const bf16x8*)&featL[(rowh + 16 + l15) * FSTR + ko];
      fb[0] = *(const bf16x8*)&W1pT[(colq + l15) * 64 + ko];
      fb[1] = *(const bf16x8*)&W1pT[(colq + 16 + l15) * 64 + ko];
      #pragma unroll
      for (int mt = 0; mt < 2; ++mt) {
        acch[mt][0] = MFMA16(fa[mt], fb[0], acch[mt][0]);
        acch[mt][1] = MFMA16(fa[mt], fb[1], acch[mt][1]);
      }
    }
    // h1 (Y) is disjoint from featL (X): safe to write before the barrier.
    #pragma unroll
    for (int mt = 0; mt < 2; ++mt)
      #pragma unroll
      for (int nt = 0; nt < 2; ++nt) {
        int col = colq + nt * 16 + l15;
        #pragma unroll
        for (int r = 0; r < 4; ++r)
          h1[(rowh + mt * 16 + quad * 4 + r) * LROW + col] =
              (__bf16)fmaxf(acch[mt][nt][r], 0.f);
      }
  }
  __syncthreads();   // featL reads done + h1 visible

  // ---- phase 2 pass 1: [A|B] rows rowh..+31, cols colq..+31 (8 accs)
  f32x4 acc1[2][4];   // nt 0,1 -> A; nt 2,3 -> B
  {
    f32x4 zero = {0.f, 0.f, 0.f, 0.f};
    #pragma unroll
    for (int mt = 0; mt < 2; ++mt)
      #pragma unroll
      for (int nt = 0; nt < 4; ++nt) acc1[mt][nt] = zero;
  }
  #pragma unroll
  for (int kb = 0; kb < 128; kb += 32) {
    const int ko = kb + quad * 8;
    bf16x8 fa[2], fb[4];
    fa[0] = *(const bf16x8*)&h1[(rowh + l15) * LROW + ko];
    fa[1] = *(const bf16x8*)&h1[(rowh + 16 + l15) * LROW + ko];
    fb[0] = *(const bf16x8*)&WabT[(colq + l15) * 128 + ko];
    fb[1] = *(const bf16x8*)&WabT[(colq + 16 + l15) * 128 + ko];
    fb[2] = *(const bf16x8*)&WabT[(128 + colq + l15) * 128 + ko];
    fb[3] = *(const bf16x8*)&WabT[(128 + colq + 16 + l15) * 128 + ko];
    #pragma unroll
    for (int mt = 0; mt < 2; ++mt)
      #pragma unroll
      for (int nt = 0; nt < 4; ++nt)
        acc1[mt][nt] = MFMA16(fa[mt], fb[nt], acc1[mt][nt]);
  }
  // write back A now (featL dead since post-phase-1 barrier)
  #pragma unroll
  for (int mt = 0; mt < 2; ++mt)
    #pragma unroll
    for (int nt = 0; nt < 2; ++nt) {
      int col = colq + nt * 16 + l15;
      #pragma unroll
      for (int r = 0; r < 4; ++r)
        Ab[(rowh + mt * 16 + quad * 4 + r) * LROW + col] = (__bf16)acc1[mt][nt][r];
    }

  // ---- phase 2 pass 2: D rows rowh..+31, cols colq..+31 (4 accs, live to ph5)
  f32x4 accD[2][2];
  {
    f32x4 zero = {0.f, 0.f, 0.f, 0.f};
    accD[0][0] = zero; accD[0][1] = zero; accD[1][0] = zero; accD[1][1] = zero;
  }
  #pragma unroll
  for (int kb = 0; kb < 128; kb += 32) {
    const int ko = kb + quad * 8;
    bf16x8 fa[2], fd[2];
    fa[0] = *(const bf16x8*)&h1[(rowh + l15) * LROW + ko];
    fa[1] = *(const bf16x8*)&h1[(rowh + 16 + l15) * LROW + ko];
    fd[0] = *(const bf16x8*)&WdT[(colq + l15) * 128 + ko];
    fd[1] = *(const bf16x8*)&WdT[(colq + 16 + l15) * 128 + ko];
    #pragma unroll
    for (int mt = 0; mt < 2; ++mt) {
      accD[mt][0] = MFMA16(fa[mt], fd[0], accD[mt][0]);
      accD[mt][1] = MFMA16(fa[mt], fd[1], accD[mt][1]);
    }
  }
  __syncthreads();   // all waves done reading h1
  // write back B over the dead h1 region
  #pragma unroll
  for (int mt = 0; mt < 2; ++mt)
    #pragma unroll
    for (int nt = 2; nt < 4; ++nt) {
      int col = colq + (nt - 2) * 16 + l15;
      #pragma unroll
      for (int r = 0; r < 4; ++r)
        Bb[(rowh + mt * 16 + quad * 4 + r) * LROW + col] = (__bf16)acc1[mt][nt][r];
    }
  __syncthreads();

  // ---- phase 4: edges, packed f32x2. One wave per graph, 2 dims/thread.
  //      S[i] = sum_{j!=i} relu(A[i]+B[j]+d_ij*w1d+cAB), in place over A.
  {
    const int g   = w;                 // graph 0..7
    const int nb2 = lane * 2;          // 2 hidden dims per thread
    const f32x2 w0 = *(const f32x2*)&vec[nb2];
    const f32x2 c0 = *(const f32x2*)&vec[128 + nb2];
    const f32x2 z2 = {0.f, 0.f};
    f32x2 B0[8];
    #pragma unroll
    for (int j = 0; j < 8; ++j) {
      unsigned vb = *(const unsigned*)&Bb[(g * 8 + j) * LROW + nb2];
      B0[j].x = bflo(vb); B0[j].y = bfhi(vb);
    }
    #pragma unroll
    for (int i = 0; i < 8; ++i) {
      unsigned va = *(const unsigned*)&Ab[(g * 8 + i) * LROW + nb2];
      f32x2 a0 = {bflo(va), bfhi(va)};
      a0 += c0;
      f32x2 s0 = z2;
      #pragma unroll
      for (int j = 0; j < 8; ++j) {
        if (j == i) continue;
        float d = dist[g * 64 + i * 8 + j];   // wave-uniform broadcast
        f32x2 d2 = {d, d};
        f32x2 t0 = __builtin_elementwise_fma(d2, w0, B0[j]) + a0;
        t0 = __builtin_elementwise_max(t0, z2);
        s0 += t0;
      }
      unsigned o = (unsigned)f2bf_u16(s0.x) | ((unsigned)f2bf_u16(s0.y) << 16);
      *(unsigned*)&Ab[(g * 8 + i) * LROW + nb2] = o;   // in-place
    }
  }
  __syncthreads();

  // ---- phase 5: ph = relu(S@Wc + D + cP); per-graph sum -> Sph (pad rows zeroed)
  {
    const __bf16* Sb = Ab;
    #pragma unroll
    for (int kb = 0; kb < 128; kb += 32) {
      const int ko = kb + quad * 8;
      bf16x8 fa[2], fc[2];
      fa[0] = *(const bf16x8*)&Sb[(rowh + l15) * LROW + ko];
      fa[1] = *(const bf16x8*)&Sb[(rowh + 16 + l15) * LROW + ko];
      fc[0] = *(const bf16x8*)&WcT[(colq + l15) * 128 + ko];
      fc[1] = *(const bf16x8*)&WcT[(colq + 16 + l15) * 128 + ko];
      #pragma unroll
      for (int mt = 0; mt < 2; ++mt) {
        accD[mt][0] = MFMA16(fa[mt], fc[0], accD[mt][0]);
        accD[mt][1] = MFMA16(fa[mt], fc[1], accD[mt][1]);
      }
    }
    #pragma unroll
    for (int mt = 0; mt < 2; ++mt)
      #pragma unroll
      for (int dt = 0; dt < 2; ++dt) {
        int col = colq + dt * 16 + l15;
        float cp = vec[256 + col];
        f32x4 a = accD[mt][dt];
        float s = fmaxf(a[0] + cp, 0.f) + fmaxf(a[1] + cp, 0.f)
                + fmaxf(a[2] + cp, 0.f) + fmaxf(a[3] + cp, 0.f);
        s += __shfl_xor(s, 16);
        int graph = rh * 4 + mt * 2 + (lane >= 32 ? 1 : 0);   // 0..7
        if ((lane & 31) < 16) Sph[graph * LROW + col] = (__bf16)s;
        else                  Sph[(8 + graph) * LROW + col] = (__bf16)0.f;
      }
  }
  __syncthreads();

  // ---- phase 6: ho = relu(Sph @ WO + cO)  (M=16: 8 graphs + 8 zero rows;
  //      8 waves x 16 cols)
  {
    const int colw6 = w * 16;
    f32x4 acco = {0.f, 0.f, 0.f, 0.f};
    #pragma unroll
    for (int kb = 0; kb < 128; kb += 32) {
      const int ko = kb + quad * 8;
      bf16x8 fa  = *(const bf16x8*)&Sph[l15 * LROW + ko];
      bf16x8 fbv = *(const bf16x8*)&WoT[(colw6 + l15) * 128 + ko];
      acco = MFMA16(fa, fbv, acco);
    }
    int col = colw6 + l15;
    float co = vec[384 + col];
    #pragma unroll
    for (int r = 0; r < 4; ++r)
      hob[(quad * 4 + r) * LROW + col] = (__bf16)fmaxf(acco[r] + co, 0.f);
  }
  __syncthreads();

  // ---- phase 7: logits = ho @ out_W2 + out_b2  (wave 0 only)
  if (w == 0) {
    f32x4 accf = {0.f, 0.f, 0.f, 0.f};
    #pragma unroll
    for (int kb = 0; kb < 128; kb += 32) {
      const int ko = kb + quad * 8;
      bf16x8 fa  = *(const bf16x8*)&hob[l15 * LROW + ko];
      bf16x8 fbv = *(const bf16x8*)&Wo2T[l15 * 128 + ko];
      accf = MFMA16(fa, fbv, accf);
    }
    if (quad < 2) {
      float b2 = out_b2[l15];
      #pragma unroll
      for (int r = 0; r < 4; ++r) {
        int row = quad * 4 + r;
        out[(g0 + row) * 16 + l15] = accf[r] + b2;
      }
    }
  }
}

extern "C" void kernel_launch(void* const* d_in, const int* in_sizes, int n_in,
                              void* d_out, int out_size, void* d_ws, size_t ws_size,
                              hipStream_t stream) {
  const int*   anchors   = (const int*)d_in[0];
  const int*   n_jumps   = (const int*)d_in[1];
  const float* positions = (const float*)d_in[2];
  const int*   colors    = (const int*)d_in[3];
  const int*   markers   = (const int*)d_in[4];
  const float* pre_W1  = (const float*)d_in[5];
  const float* pre_b1  = (const float*)d_in[6];
  const float* pre_W2  = (const float*)d_in[7];
  const float* pre_b2  = (const float*)d_in[8];
  const float* msg_W1  = (const float*)d_in[9];
  const float* msg_b1  = (const float*)d_in[10];
  const float* msg_W2  = (const float*)d_in[11];
  const float* msg_b2  = (const float*)d_in[12];
  const float* post_W1 = (const float*)d_in[13];
  const float* post_b1 = (const float*)d_in[14];
  const float* post_W2 = (const float*)d_in[15];
  const float* post_b2 = (const float*)d_in[16];
  const float* out_W1  = (const float*)d_in[17];
  const float* out_b1  = (const float*)d_in[18];
  const float* out_W2  = (const float*)d_in[19];
  const float* out_b2  = (const float*)d_in[20];

  char* ws = (char*)d_ws;
  unsigned short* WabT = (unsigned short*)(ws);            // [256][128] bf16
  unsigned short* WdT  = (unsigned short*)(ws + 65536);    // [128][128]
  unsigned short* WcT  = (unsigned short*)(ws + 98304);    // [128][128]
  unsigned short* WoT  = (unsigned short*)(ws + 131072);   // [128][128]
  unsigned short* Wo2T = (unsigned short*)(ws + 163840);   // [16][128]
  float*          vecs = (float*)(ws + 167936);            // 512 f32
  unsigned short* W1pT = (unsigned short*)(ws + 169984);   // [128][64] bf16

  const int BS = in_sizes[0];

  combine_weights<<<324, 256, 0, stream>>>(
      pre_W1, pre_b1, pre_W2, msg_W1, msg_W2, post_W1, post_W2, out_W1, out_W2,
      pre_b2, msg_b1, msg_b2, post_b1, post_b2, out_b1,
      WabT, WdT, WcT, WoT, Wo2T, W1pT, vecs);

  rrn_main<<<BS / 8, 512, 0, stream>>>(
      anchors, n_jumps, positions, colors, markers,
      (const __bf16*)W1pT,
      (const __bf16*)WabT, (const __bf16*)WdT, (const __bf16*)WcT,
      (const __bf16*)WoT, (const __bf16*)Wo2T, vecs, out_b2, (float*)d_out);
}

// Round 9
// 155.732 us; speedup vs baseline: 1.1804x; 1.1804x over previous
//
#include <hip/hip_runtime.h>

#define LROW 136   // padded LDS row stride in bf16 elements (128 + 8); 272 B rows
#define FSTR 72    // feat row stride in bf16 (64 K-cols + 8 pad); 144 B rows

typedef __bf16 bf16x8  __attribute__((ext_vector_type(8)));
typedef float  f32x4   __attribute__((ext_vector_type(4)));
typedef float  f32x2   __attribute__((ext_vector_type(2)));

#define MFMA16(a, b, c) __builtin_amdgcn_mfma_f32_16x16x32_bf16((a), (b), (c), 0, 0, 0)

__device__ __forceinline__ float bflo(unsigned v) { return __uint_as_float(v << 16); }
__device__ __forceinline__ float bfhi(unsigned v) { return __uint_as_float(v & 0xffff0000u); }

__device__ __forceinline__ unsigned short f2bf_u16(float f) {
  unsigned u = __float_as_uint(f);
  u += 0x7fffu + ((u >> 16) & 1u);
  return (unsigned short)(u >> 16);
}

// ---------------------------------------------------------------------------
// Kernel 1: fold linear layers into combined weight matrices (bf16, [n][k]
// transposed layout) + folded bias vectors (f32) + W1pT (pre_W1 transposed,
// bias folded as feature k=42, zero-padded to K=64).
// ---------------------------------------------------------------------------
__global__ void combine_weights(
    const float* __restrict__ pre_W1, const float* __restrict__ pre_b1,
    const float* __restrict__ pre_W2, const float* __restrict__ msg_W1,
    const float* __restrict__ msg_W2, const float* __restrict__ post_W1,
    const float* __restrict__ post_W2, const float* __restrict__ out_W1,
    const float* __restrict__ out_W2, const float* __restrict__ pre_b2,
    const float* __restrict__ msg_b1, const float* __restrict__ msg_b2,
    const float* __restrict__ post_b1, const float* __restrict__ post_b2,
    const float* __restrict__ out_b1,
    unsigned short* __restrict__ WabT, unsigned short* __restrict__ WdT,
    unsigned short* __restrict__ WcT, unsigned short* __restrict__ WoT,
    unsigned short* __restrict__ Wo2T, unsigned short* __restrict__ W1pT,
    float* __restrict__ vecs)
{
  __shared__ float part[256];
  const int b = blockIdx.x;
  const int t = threadIdx.x;
  if (b < 320) {
    const int p  = b >> 6;
    const int kp = b & 63;
    const int k  = kp * 2 + (t >> 7);
    const int n  = t & 127;
    const float* L; const float* R; unsigned short* O;
    if (p == 0)      { L = pre_W2;  R = msg_W1;             O = WabT; }
    else if (p == 1) { L = pre_W2;  R = msg_W1 + 128*128;   O = WabT + 128*128; }
    else if (p == 2) { L = pre_W2;  R = post_W1 + 128*128;  O = WdT; }
    else if (p == 3) { L = msg_W2;  R = post_W1;            O = WcT; }
    else             { L = post_W2; R = out_W1;             O = WoT; }
    const float* Lr = L + k * 128;
    float a0 = 0.f, a1 = 0.f, a2 = 0.f, a3 = 0.f;
    #pragma unroll 8
    for (int m = 0; m < 128; m += 4) {
      a0 = fmaf(Lr[m + 0], R[(m + 0) * 128 + n], a0);
      a1 = fmaf(Lr[m + 1], R[(m + 1) * 128 + n], a1);
      a2 = fmaf(Lr[m + 2], R[(m + 2) * 128 + n], a2);
      a3 = fmaf(Lr[m + 3], R[(m + 3) * 128 + n], a3);
    }
    O[n * 128 + k] = f2bf_u16((a0 + a1) + (a2 + a3));
  } else if (b == 320) {
    // Wo2T transpose, w1d copy, W1pT build
    for (int idx = t; idx < 16 * 128; idx += 256) {
      int o = idx >> 7, k = idx & 127;
      Wo2T[o * 128 + k] = f2bf_u16(out_W2[k * 16 + o]);
    }
    if (t < 128) vecs[t] = msg_W1[256 * 128 + t];          // w1d
    for (int idx = t; idx < 128 * 64; idx += 256) {
      int n = idx >> 6, k = idx & 63;
      float v = (k < 42) ? pre_W1[k * 128 + n] : (k == 42 ? pre_b1[n] : 0.f);
      W1pT[n * 64 + k] = f2bf_u16(v);
    }
  } else {
    const int n = t & 127;
    const int h = t >> 7;
    float s = 0.f;
    if (b == 321) {            // cAB = pre_b2@(W1a+W1b) + msg_b1
      #pragma unroll 8
      for (int m = h * 64; m < h * 64 + 64; ++m)
        s = fmaf(pre_b2[m], msg_W1[m * 128 + n] + msg_W1[(128 + m) * 128 + n], s);
    } else if (b == 322) {     // cP = 7*msg_b2@P1a + pre_b2@P1b + post_b1
      #pragma unroll 8
      for (int m = h * 64; m < h * 64 + 64; ++m) {
        s = fmaf(7.f * msg_b2[m], post_W1[m * 128 + n], s);
        s = fmaf(pre_b2[m], post_W1[(128 + m) * 128 + n], s);
      }
    } else {                   // cO = 8*post_b2@out_W1 + out_b1
      #pragma unroll 8
      for (int m = h * 64; m < h * 64 + 64; ++m)
        s = fmaf(8.f * post_b2[m], out_W1[m * 128 + n], s);
    }
    part[t] = s;
    __syncthreads();
    if (t < 128) {
      float r = part[t] + part[t + 128];
      if (b == 321)      vecs[128 + t] = r + msg_b1[t];
      else if (b == 322) vecs[256 + t] = r + post_b1[t];
      else               vecs[384 + t] = r + out_b1[t];
    }
  }
}

// ---------------------------------------------------------------------------
// Kernel 2: fully fused RRN. R9 = R7 (best: 57us) with two barriers removed:
//   (i) mid-phase-1 barrier (h1 region disjoint from featL);
//   (ii) post-B-write barrier: phase 4 remapped to OWN-COLUMN access (wave w
//        touches only cols colq..colq+31 of A/B/S, which it wrote itself) so
//        wave-internal lgkmcnt ordering suffices.
// Lessons encoded: R6/R8 showed occupancy is anti-correlated here (barrier
// convoy widens); keep 8 graphs x 256 threads x 4 blocks/CU and shorten the
// per-wave critical path instead.
// ---------------------------------------------------------------------------
__global__ void __launch_bounds__(256, 4) rrn_main(
    const int* __restrict__ anchors, const int* __restrict__ n_jumps,
    const float* __restrict__ positions, const int* __restrict__ colors,
    const int* __restrict__ markers,
    const __bf16* __restrict__ W1pT,
    const __bf16* __restrict__ WabT, const __bf16* __restrict__ WdT,
    const __bf16* __restrict__ WcT, const __bf16* __restrict__ WoT,
    const __bf16* __restrict__ Wo2T, const float* __restrict__ vecs,
    const float* __restrict__ out_b2, float* __restrict__ out)
{
  __shared__ __align__(16) char smem[38912];
  // X [0,17408): phases 0-1: featL bf16[64][FSTR] (9216 B). Phase 2+: Ab
  //   bf16[64][LROW] (A, then S in place).
  // Y [17408,34816): h1 bf16[64][LROW] (phases 1-2); Bb after h1-drain;
  //   Sph @17408 / hob @21760 (phases 5+).
  // dist f32[512] @34816; vec f32[512] @36864.
  __bf16* featL = (__bf16*)(smem);
  __bf16* Ab    = (__bf16*)(smem);
  __bf16* h1    = (__bf16*)(smem + 17408);
  __bf16* Bb    = (__bf16*)(smem + 17408);
  __bf16* Sph   = (__bf16*)(smem + 17408);
  __bf16* hob   = (__bf16*)(smem + 21760);
  float*  dist  = (float*)(smem + 34816);
  float*  vec   = (float*)(smem + 36864);

  const int tid  = threadIdx.x;
  const int lane = tid & 63;
  const int w    = tid >> 6;      // wave 0..3
  const int l15  = lane & 15;
  const int quad = lane >> 4;
  const int colw = w * 32;        // this wave's 32-col slice
  const int g0   = blockIdx.x * 8;
  const int n0   = blockIdx.x * 64;

  // ---- phase 0: build feature rows (thread-private: no race), dist, vec
  if (tid < 64) {
    uint4* rp = (uint4*)&featL[tid * FSTR];   // 144 B row, 16B-aligned
    uint4 z4 = {0u, 0u, 0u, 0u};
    #pragma unroll
    for (int i = 0; i < 9; ++i) rp[i] = z4;
    int g = tid >> 3;
    float px = positions[(n0 + tid) * 2], py = positions[(n0 + tid) * 2 + 1];
    int c  = colors[n0 + tid], mk = markers[n0 + tid] - 8;
    int a  = anchors[g0 + g],  nj = n_jumps[g0 + g];
    __bf16* row = &featL[tid * FSTR];
    row[0] = (__bf16)px; row[1] = (__bf16)py;
    const __bf16 one = (__bf16)1.f;
    row[2 + c] = one; row[10 + mk] = one;
    row[18 + a] = one; row[34 + nj] = one;
    row[42] = one;                              // bias-as-feature
  }
  for (int i = tid; i < 512; i += 256) {
    int g = i >> 6, ii = (i >> 3) & 7, jj = i & 7;
    const float* pa = positions + (n0 + g * 8 + ii) * 2;
    const float* pb = positions + (n0 + g * 8 + jj) * 2;
    float dx = pa[0] - pb[0], dy = pa[1] - pb[1];
    dist[i] = sqrtf(dx * dx + dy * dy);
  }
  for (int i = tid; i < 512; i += 256) vec[i] = vecs[i];
  __syncthreads();

  // ---- phase 1: h1 = relu(featL @ W1pT) via MFMA (M=64, N=128, K=64 padded).
  //      h1 (Y) disjoint from featL (X): single barrier after writes.
  {
    f32x4 acch[4][2];
    f32x4 zero = {0.f, 0.f, 0.f, 0.f};
    #pragma unroll
    for (int mt = 0; mt < 4; ++mt) { acch[mt][0] = zero; acch[mt][1] = zero; }
    #pragma unroll
    for (int kb = 0; kb < 64; kb += 32) {
      const int ko = kb + quad * 8;
      bf16x8 fa[4], fb[2];
      #pragma unroll
      for (int mt = 0; mt < 4; ++mt)
        fa[mt] = *(const bf16x8*)&featL[(mt * 16 + l15) * FSTR + ko];
      fb[0] = *(const bf16x8*)&W1pT[(colw + l15) * 64 + ko];
      fb[1] = *(const bf16x8*)&W1pT[(colw + 16 + l15) * 64 + ko];
      #pragma unroll
      for (int mt = 0; mt < 4; ++mt) {
        acch[mt][0] = MFMA16(fa[mt], fb[0], acch[mt][0]);
        acch[mt][1] = MFMA16(fa[mt], fb[1], acch[mt][1]);
      }
    }
    #pragma unroll
    for (int mt = 0; mt < 4; ++mt)
      #pragma unroll
      for (int nt = 0; nt < 2; ++nt) {
        int col = colw + nt * 16 + l15;
        #pragma unroll
        for (int r = 0; r < 4; ++r)
          h1[(mt * 16 + quad * 4 + r) * LROW + col] =
              (__bf16)fmaxf(acch[mt][nt][r], 0.f);
      }
  }
  __syncthreads();   // featL reads done + h1 visible

  // ---- phase 2 pass 1: [A|B] cols colw..colw+31 = h1 @ WabT (16 accs)
  f32x4 acc1[4][4];   // nt 0,1 -> A; nt 2,3 -> B
  {
    f32x4 zero = {0.f, 0.f, 0.f, 0.f};
    #pragma unroll
    for (int mt = 0; mt < 4; ++mt)
      #pragma unroll
      for (int nt = 0; nt < 4; ++nt) acc1[mt][nt] = zero;
  }
  #pragma unroll
  for (int kb = 0; kb < 128; kb += 32) {
    const int ko = kb + quad * 8;
    bf16x8 fa[4], fb[4];
    #pragma unroll
    for (int mt = 0; mt < 4; ++mt)
      fa[mt] = *(const bf16x8*)&h1[(mt * 16 + l15) * LROW + ko];
    fb[0] = *(const bf16x8*)&WabT[(colw + l15) * 128 + ko];
    fb[1] = *(const bf16x8*)&WabT[(colw + 16 + l15) * 128 + ko];
    fb[2] = *(const bf16x8*)&WabT[(128 + colw + l15) * 128 + ko];
    fb[3] = *(const bf16x8*)&WabT[(128 + colw + 16 + l15) * 128 + ko];
    #pragma unroll
    for (int mt = 0; mt < 4; ++mt)
      #pragma unroll
      for (int nt = 0; nt < 4; ++nt)
        acc1[mt][nt] = MFMA16(fa[mt], fb[nt], acc1[mt][nt]);
  }
  // write back A now (featL dead since post-phase-1 barrier); own cols only.
  #pragma unroll
  for (int mt = 0; mt < 4; ++mt)
    #pragma unroll
    for (int nt = 0; nt < 2; ++nt) {
      int col = colw + nt * 16 + l15;
      #pragma unroll
      for (int r = 0; r < 4; ++r)
        Ab[(mt * 16 + quad * 4 + r) * LROW + col] = (__bf16)acc1[mt][nt][r];
    }

  // ---- phase 2 pass 2: D cols colw..colw+31 = h1 @ WdT (8 accs, live to ph5)
  f32x4 accD[4][2];
  {
    f32x4 zero = {0.f, 0.f, 0.f, 0.f};
    #pragma unroll
    for (int mt = 0; mt < 4; ++mt) { accD[mt][0] = zero; accD[mt][1] = zero; }
  }
  #pragma unroll
  for (int kb = 0; kb < 128; kb += 32) {
    const int ko = kb + quad * 8;
    bf16x8 fa[4], fd[2];
    #pragma unroll
    for (int mt = 0; mt < 4; ++mt)
      fa[mt] = *(const bf16x8*)&h1[(mt * 16 + l15) * LROW + ko];
    fd[0] = *(const bf16x8*)&WdT[(colw + l15) * 128 + ko];
    fd[1] = *(const bf16x8*)&WdT[(colw + 16 + l15) * 128 + ko];
    #pragma unroll
    for (int mt = 0; mt < 4; ++mt) {
      accD[mt][0] = MFMA16(fa[mt], fd[0], accD[mt][0]);
      accD[mt][1] = MFMA16(fa[mt], fd[1], accD[mt][1]);
    }
  }
  __syncthreads();   // h1 drain: all waves done reading Y before B overwrites it
  // write back B over the dead h1 region; own cols only -> NO barrier after.
  #pragma unroll
  for (int mt = 0; mt < 4; ++mt)
    #pragma unroll
    for (int nt = 2; nt < 4; ++nt) {
      int col = colw + (nt - 2) * 16 + l15;
      #pragma unroll
      for (int r = 0; r < 4; ++r)
        Bb[(mt * 16 + quad * 4 + r) * LROW + col] = (__bf16)acc1[mt][nt][r];
    }

  // ---- phase 4: edges, OWN-COLUMN mapping (no barrier since B write):
  //      wave w covers its cols colw..+31; quad -> graph pair; lane l15 ->
  //      adjacent col pair. S[i] = sum_{j!=i} relu(A[i]+B[j]+d_ij*w1d+cAB),
  //      written in place over A (same wave-owned cols).
  {
    const int c0 = colw + ((l15 & 8) << 1) + 2 * (l15 & 7);  // adjacent pair c0,c0+1
    const f32x2 wv = { vec[c0], vec[c0 + 1] };
    const f32x2 cv = { vec[128 + c0], vec[128 + c0 + 1] };
    const f32x2 z2 = {0.f, 0.f};
    #pragma unroll
    for (int gi = 0; gi < 2; ++gi) {
      const int g = 2 * quad + gi;
      f32x2 Bj[8];
      #pragma unroll
      for (int j = 0; j < 8; ++j) {
        unsigned vb = *(const unsigned*)&Bb[(g * 8 + j) * LROW + c0];
        Bj[j].x = bflo(vb); Bj[j].y = bfhi(vb);
      }
      #pragma unroll
      for (int i = 0; i < 8; ++i) {
        unsigned va = *(const unsigned*)&Ab[(g * 8 + i) * LROW + c0];
        f32x2 a = {bflo(va) + cv.x, bfhi(va) + cv.y};
        f32x2 s = z2;
        #pragma unroll
        for (int j = 0; j < 8; ++j) {
          if (j == i) continue;
          float d = dist[g * 64 + i * 8 + j];
          f32x2 d2 = {d, d};
          f32x2 t = __builtin_elementwise_fma(d2, wv, Bj[j]) + a;
          s += __builtin_elementwise_max(t, z2);
        }
        unsigned o = (unsigned)f2bf_u16(s.x) | ((unsigned)f2bf_u16(s.y) << 16);
        *(unsigned*)&Ab[(g * 8 + i) * LROW + c0] = o;   // in-place S
      }
    }
  }
  __syncthreads();   // S visible to all waves

  // ---- phase 5: ph = relu(S@Wc + D + cP); per-graph sum -> Sph (pad rows zeroed)
  {
    const __bf16* Sb = Ab;
    #pragma unroll
    for (int kb = 0; kb < 128; kb += 32) {
      const int ko = kb + quad * 8;
      bf16x8 fa[4], fc[2];
      #pragma unroll
      for (int mt = 0; mt < 4; ++mt)
        fa[mt] = *(const bf16x8*)&Sb[(mt * 16 + l15) * LROW + ko];
      fc[0] = *(const bf16x8*)&WcT[(colw + l15) * 128 + ko];
      fc[1] = *(const bf16x8*)&WcT[(colw + 16 + l15) * 128 + ko];
      #pragma unroll
      for (int mt = 0; mt < 4; ++mt) {
        accD[mt][0] = MFMA16(fa[mt], fc[0], accD[mt][0]);
        accD[mt][1] = MFMA16(fa[mt], fc[1], accD[mt][1]);
      }
    }
    #pragma unroll
    for (int mt = 0; mt < 4; ++mt)
      #pragma unroll
      for (int dt = 0; dt < 2; ++dt) {
        int col = colw + dt * 16 + l15;
        float cp = vec[256 + col];
        f32x4 a = accD[mt][dt];
        float s = fmaxf(a[0] + cp, 0.f) + fmaxf(a[1] + cp, 0.f)
                + fmaxf(a[2] + cp, 0.f) + fmaxf(a[3] + cp, 0.f);
        s += __shfl_xor(s, 16);
        int grow = mt * 2 + (lane >= 32 ? 1 : 0);
        if ((lane & 31) < 16) Sph[grow * LROW + col] = (__bf16)s;
        else                  Sph[(8 + grow) * LROW + col] = (__bf16)0.f;
      }
  }
  __syncthreads();

  // ---- phase 6: ho = relu(Sph @ WO + cO)  (M=16 tile: 8 graphs + 8 zero rows)
  {
    f32x4 acco[2];
    f32x4 zero = {0.f, 0.f, 0.f, 0.f};
    acco[0] = zero; acco[1] = zero;
    #pragma unroll
    for (int kb = 0; kb < 128; kb += 32) {
      const int ko = kb + quad * 8;
      bf16x8 fa = *(const bf16x8*)&Sph[l15 * LROW + ko];
      bf16x8 fb0 = *(const bf16x8*)&WoT[(colw + l15) * 128 + ko];
      bf16x8 fb1 = *(const bf16x8*)&WoT[(colw + 16 + l15) * 128 + ko];
      acco[0] = MFMA16(fa, fb0, acco[0]);
      acco[1] = MFMA16(fa, fb1, acco[1]);
    }
    #pragma unroll
    for (int dt = 0; dt < 2; ++dt) {
      int col = colw + dt * 16 + l15;
      float co = vec[384 + col];
      #pragma unroll
      for (int r = 0; r < 4; ++r)
        hob[(quad * 4 + r) * LROW + col] = (__bf16)fmaxf(acco[dt][r] + co, 0.f);
    }
  }
  __syncthreads();

  // ---- phase 7: logits = ho @ out_W2 + out_b2  (wave 0 only)
  if (w == 0) {
    f32x4 accf = {0.f, 0.f, 0.f, 0.f};
    #pragma unroll
    for (int kb = 0; kb < 128; kb += 32) {
      const int ko = kb + quad * 8;
      bf16x8 fa  = *(const bf16x8*)&hob[l15 * LROW + ko];
      bf16x8 fbv = *(const bf16x8*)&Wo2T[l15 * 128 + ko];
      accf = MFMA16(fa, fbv, accf);
    }
    if (quad < 2) {
      float b2 = out_b2[l15];
      #pragma unroll
      for (int r = 0; r < 4; ++r) {
        int row = quad * 4 + r;
        out[(g0 + row) * 16 + l15] = accf[r] + b2;
      }
    }
  }
}

extern "C" void kernel_launch(void* const* d_in, const int* in_sizes, int n_in,
                              void* d_out, int out_size, void* d_ws, size_t ws_size,
                              hipStream_t stream) {
  const int*   anchors   = (const int*)d_in[0];
  const int*   n_jumps   = (const int*)d_in[1];
  const float* positions = (const float*)d_in[2];
  const int*   colors    = (const int*)d_in[3];
  const int*   markers   = (const int*)d_in[4];
  const float* pre_W1  = (const float*)d_in[5];
  const float* pre_b1  = (const float*)d_in[6];
  const float* pre_W2  = (const float*)d_in[7];
  const float* pre_b2  = (const float*)d_in[8];
  const float* msg_W1  = (const float*)d_in[9];
  const float* msg_b1  = (const float*)d_in[10];
  const float* msg_W2  = (const float*)d_in[11];
  const float* msg_b2  = (const float*)d_in[12];
  const float* post_W1 = (const float*)d_in[13];
  const float* post_b1 = (const float*)d_in[14];
  const float* post_W2 = (const float*)d_in[15];
  const float* post_b2 = (const float*)d_in[16];
  const float* out_W1  = (const float*)d_in[17];
  const float* out_b1  = (const float*)d_in[18];
  const float* out_W2  = (const float*)d_in[19];
  const float* out_b2  = (const float*)d_in[20];

  char* ws = (char*)d_ws;
  unsigned short* WabT = (unsigned short*)(ws);            // [256][128] bf16
  unsigned short* WdT  = (unsigned short*)(ws + 65536);    // [128][128]
  unsigned short* WcT  = (unsigned short*)(ws + 98304);    // [128][128]
  unsigned short* WoT  = (unsigned short*)(ws + 131072);   // [128][128]
  unsigned short* Wo2T = (unsigned short*)(ws + 163840);   // [16][128]
  float*          vecs = (float*)(ws + 167936);            // 512 f32
  unsigned short* W1pT = (unsigned short*)(ws + 169984);   // [128][64] bf16

  const int BS = in_sizes[0];

  combine_weights<<<324, 256, 0, stream>>>(
      pre_W1, pre_b1, pre_W2, msg_W1, msg_W2, post_W1, post_W2, out_W1, out_W2,
      pre_b2, msg_b1, msg_b2, post_b1, post_b2, out_b1,
      WabT, WdT, WcT, WoT, Wo2T, W1pT, vecs);

  rrn_main<<<BS / 8, 256, 0, stream>>>(
      anchors, n_jumps, positions, colors, markers,
      (const __bf16*)W1pT,
      (const __bf16*)WabT, (const __bf16*)WdT, (const __bf16*)WcT,
      (const __bf16*)WoT, (const __bf16*)Wo2T, vecs, out_b2, (float*)d_out);
}

// Round 11
// 153.384 us; speedup vs baseline: 1.1984x; 1.0153x over previous
//
#include <hip/hip_runtime.h>

#define LROW 136   // padded LDS row stride in bf16 elements (128 + 8); 272 B rows
#define FSTR 72    // feat row stride in bf16 (64 K-cols + 8 pad); 144 B rows

typedef __bf16 bf16x8  __attribute__((ext_vector_type(8)));
typedef float  f32x4   __attribute__((ext_vector_type(4)));
typedef float  f32x2   __attribute__((ext_vector_type(2)));

#define MFMA16(a, b, c) __builtin_amdgcn_mfma_f32_16x16x32_bf16((a), (b), (c), 0, 0, 0)

__device__ __forceinline__ float bflo(unsigned v) { return __uint_as_float(v << 16); }
__device__ __forceinline__ float bfhi(unsigned v) { return __uint_as_float(v & 0xffff0000u); }

__device__ __forceinline__ unsigned short f2bf_u16(float f) {
  unsigned u = __float_as_uint(f);
  u += 0x7fffu + ((u >> 16) & 1u);
  return (unsigned short)(u >> 16);
}

// ---------------------------------------------------------------------------
// Kernel 1: fold linear layers into combined weight matrices (bf16, [n][k]
// transposed layout) + folded bias vectors (f32) + W1pT (pre_W1 transposed,
// bias folded as feature k=42, zero-padded to K=64).
// ---------------------------------------------------------------------------
__global__ void combine_weights(
    const float* __restrict__ pre_W1, const float* __restrict__ pre_b1,
    const float* __restrict__ pre_W2, const float* __restrict__ msg_W1,
    const float* __restrict__ msg_W2, const float* __restrict__ post_W1,
    const float* __restrict__ post_W2, const float* __restrict__ out_W1,
    const float* __restrict__ out_W2, const float* __restrict__ pre_b2,
    const float* __restrict__ msg_b1, const float* __restrict__ msg_b2,
    const float* __restrict__ post_b1, const float* __restrict__ post_b2,
    const float* __restrict__ out_b1,
    unsigned short* __restrict__ WabT, unsigned short* __restrict__ WdT,
    unsigned short* __restrict__ WcT, unsigned short* __restrict__ WoT,
    unsigned short* __restrict__ Wo2T, unsigned short* __restrict__ W1pT,
    float* __restrict__ vecs)
{
  __shared__ float part[256];
  const int b = blockIdx.x;
  const int t = threadIdx.x;
  if (b < 320) {
    const int p  = b >> 6;
    const int kp = b & 63;
    const int k  = kp * 2 + (t >> 7);
    const int n  = t & 127;
    const float* L; const float* R; unsigned short* O;
    if (p == 0)      { L = pre_W2;  R = msg_W1;             O = WabT; }
    else if (p == 1) { L = pre_W2;  R = msg_W1 + 128*128;   O = WabT + 128*128; }
    else if (p == 2) { L = pre_W2;  R = post_W1 + 128*128;  O = WdT; }
    else if (p == 3) { L = msg_W2;  R = post_W1;            O = WcT; }
    else             { L = post_W2; R = out_W1;             O = WoT; }
    const float* Lr = L + k * 128;
    float a0 = 0.f, a1 = 0.f, a2 = 0.f, a3 = 0.f;
    #pragma unroll 8
    for (int m = 0; m < 128; m += 4) {
      a0 = fmaf(Lr[m + 0], R[(m + 0) * 128 + n], a0);
      a1 = fmaf(Lr[m + 1], R[(m + 1) * 128 + n], a1);
      a2 = fmaf(Lr[m + 2], R[(m + 2) * 128 + n], a2);
      a3 = fmaf(Lr[m + 3], R[(m + 3) * 128 + n], a3);
    }
    O[n * 128 + k] = f2bf_u16((a0 + a1) + (a2 + a3));
  } else if (b == 320) {
    // Wo2T transpose, w1d copy, W1pT build
    for (int idx = t; idx < 16 * 128; idx += 256) {
      int o = idx >> 7, k = idx & 127;
      Wo2T[o * 128 + k] = f2bf_u16(out_W2[k * 16 + o]);
    }
    if (t < 128) vecs[t] = msg_W1[256 * 128 + t];          // w1d
    for (int idx = t; idx < 128 * 64; idx += 256) {
      int n = idx >> 6, k = idx & 63;
      float v = (k < 42) ? pre_W1[k * 128 + n] : (k == 42 ? pre_b1[n] : 0.f);
      W1pT[n * 64 + k] = f2bf_u16(v);
    }
  } else {
    const int n = t & 127;
    const int h = t >> 7;
    float s = 0.f;
    if (b == 321) {            // cAB = pre_b2@(W1a+W1b) + msg_b1
      #pragma unroll 8
      for (int m = h * 64; m < h * 64 + 64; ++m)
        s = fmaf(pre_b2[m], msg_W1[m * 128 + n] + msg_W1[(128 + m) * 128 + n], s);
    } else if (b == 322) {     // cP = 7*msg_b2@P1a + pre_b2@P1b + post_b1
      #pragma unroll 8
      for (int m = h * 64; m < h * 64 + 64; ++m) {
        s = fmaf(7.f * msg_b2[m], post_W1[m * 128 + n], s);
        s = fmaf(pre_b2[m], post_W1[(128 + m) * 128 + n], s);
      }
    } else {                   // cO = 8*post_b2@out_W1 + out_b1
      #pragma unroll 8
      for (int m = h * 64; m < h * 64 + 64; ++m)
        s = fmaf(8.f * post_b2[m], out_W1[m * 128 + n], s);
    }
    part[t] = s;
    __syncthreads();
    if (t < 128) {
      float r = part[t] + part[t + 128];
      if (b == 321)      vecs[128 + t] = r + msg_b1[t];
      else if (b == 322) vecs[256 + t] = r + post_b1[t];
      else               vecs[384 + t] = r + out_b1[t];
    }
  }
}

// ---------------------------------------------------------------------------
// Kernel 2: fully fused RRN (R9 structure, known-good 57us): 8 graphs x 256
// threads x 4 blocks/CU, 6 barriers, MFMA feature layer, own-column phase 4.
// R10's fragment-major weight relayout failed correctness despite apparent
// bit-equivalence -- reverted per rigor discipline.
// ---------------------------------------------------------------------------
__global__ void __launch_bounds__(256, 4) rrn_main(
    const int* __restrict__ anchors, const int* __restrict__ n_jumps,
    const float* __restrict__ positions, const int* __restrict__ colors,
    const int* __restrict__ markers,
    const __bf16* __restrict__ W1pT,
    const __bf16* __restrict__ WabT, const __bf16* __restrict__ WdT,
    const __bf16* __restrict__ WcT, const __bf16* __restrict__ WoT,
    const __bf16* __restrict__ Wo2T, const float* __restrict__ vecs,
    const float* __restrict__ out_b2, float* __restrict__ out)
{
  __shared__ __align__(16) char smem[38912];
  // X [0,17408): phases 0-1: featL bf16[64][FSTR] (9216 B). Phase 2+: Ab
  //   bf16[64][LROW] (A, then S in place).
  // Y [17408,34816): h1 bf16[64][LROW] (phases 1-2); Bb after h1-drain;
  //   Sph @17408 / hob @21760 (phases 5+).
  // dist f32[512] @34816; vec f32[512] @36864.
  __bf16* featL = (__bf16*)(smem);
  __bf16* Ab    = (__bf16*)(smem);
  __bf16* h1    = (__bf16*)(smem + 17408);
  __bf16* Bb    = (__bf16*)(smem + 17408);
  __bf16* Sph   = (__bf16*)(smem + 17408);
  __bf16* hob   = (__bf16*)(smem + 21760);
  float*  dist  = (float*)(smem + 34816);
  float*  vec   = (float*)(smem + 36864);

  const int tid  = threadIdx.x;
  const int lane = tid & 63;
  const int w    = tid >> 6;      // wave 0..3
  const int l15  = lane & 15;
  const int quad = lane >> 4;
  const int colw = w * 32;        // this wave's 32-col slice
  const int g0   = blockIdx.x * 8;
  const int n0   = blockIdx.x * 64;

  // ---- phase 0: build feature rows (thread-private: no race), dist, vec
  if (tid < 64) {
    uint4* rp = (uint4*)&featL[tid * FSTR];   // 144 B row, 16B-aligned
    uint4 z4 = {0u, 0u, 0u, 0u};
    #pragma unroll
    for (int i = 0; i < 9; ++i) rp[i] = z4;
    int g = tid >> 3;
    float px = positions[(n0 + tid) * 2], py = positions[(n0 + tid) * 2 + 1];
    int c  = colors[n0 + tid], mk = markers[n0 + tid] - 8;
    int a  = anchors[g0 + g],  nj = n_jumps[g0 + g];
    __bf16* row = &featL[tid * FSTR];
    row[0] = (__bf16)px; row[1] = (__bf16)py;
    const __bf16 one = (__bf16)1.f;
    row[2 + c] = one; row[10 + mk] = one;
    row[18 + a] = one; row[34 + nj] = one;
    row[42] = one;                              // bias-as-feature
  }
  for (int i = tid; i < 512; i += 256) {
    int g = i >> 6, ii = (i >> 3) & 7, jj = i & 7;
    const float* pa = positions + (n0 + g * 8 + ii) * 2;
    const float* pb = positions + (n0 + g * 8 + jj) * 2;
    float dx = pa[0] - pb[0], dy = pa[1] - pb[1];
    dist[i] = sqrtf(dx * dx + dy * dy);
  }
  for (int i = tid; i < 512; i += 256) vec[i] = vecs[i];
  __syncthreads();

  // ---- phase 1: h1 = relu(featL @ W1pT) via MFMA (M=64, N=128, K=64 padded).
  //      h1 (Y) disjoint from featL (X): single barrier after writes.
  {
    f32x4 acch[4][2];
    f32x4 zero = {0.f, 0.f, 0.f, 0.f};
    #pragma unroll
    for (int mt = 0; mt < 4; ++mt) { acch[mt][0] = zero; acch[mt][1] = zero; }
    #pragma unroll
    for (int kb = 0; kb < 64; kb += 32) {
      const int ko = kb + quad * 8;
      bf16x8 fa[4], fb[2];
      #pragma unroll
      for (int mt = 0; mt < 4; ++mt)
        fa[mt] = *(const bf16x8*)&featL[(mt * 16 + l15) * FSTR + ko];
      fb[0] = *(const bf16x8*)&W1pT[(colw + l15) * 64 + ko];
      fb[1] = *(const bf16x8*)&W1pT[(colw + 16 + l15) * 64 + ko];
      #pragma unroll
      for (int mt = 0; mt < 4; ++mt) {
        acch[mt][0] = MFMA16(fa[mt], fb[0], acch[mt][0]);
        acch[mt][1] = MFMA16(fa[mt], fb[1], acch[mt][1]);
      }
    }
    #pragma unroll
    for (int mt = 0; mt < 4; ++mt)
      #pragma unroll
      for (int nt = 0; nt < 2; ++nt) {
        int col = colw + nt * 16 + l15;
        #pragma unroll
        for (int r = 0; r < 4; ++r)
          h1[(mt * 16 + quad * 4 + r) * LROW + col] =
              (__bf16)fmaxf(acch[mt][nt][r], 0.f);
      }
  }
  __syncthreads();   // featL reads done + h1 visible

  // ---- phase 2 pass 1: [A|B] cols colw..colw+31 = h1 @ WabT (16 accs)
  f32x4 acc1[4][4];   // nt 0,1 -> A; nt 2,3 -> B
  {
    f32x4 zero = {0.f, 0.f, 0.f, 0.f};
    #pragma unroll
    for (int mt = 0; mt < 4; ++mt)
      #pragma unroll
      for (int nt = 0; nt < 4; ++nt) acc1[mt][nt] = zero;
  }
  #pragma unroll
  for (int kb = 0; kb < 128; kb += 32) {
    const int ko = kb + quad * 8;
    bf16x8 fa[4], fb[4];
    #pragma unroll
    for (int mt = 0; mt < 4; ++mt)
      fa[mt] = *(const bf16x8*)&h1[(mt * 16 + l15) * LROW + ko];
    fb[0] = *(const bf16x8*)&WabT[(colw + l15) * 128 + ko];
    fb[1] = *(const bf16x8*)&WabT[(colw + 16 + l15) * 128 + ko];
    fb[2] = *(const bf16x8*)&WabT[(128 + colw + l15) * 128 + ko];
    fb[3] = *(const bf16x8*)&WabT[(128 + colw + 16 + l15) * 128 + ko];
    #pragma unroll
    for (int mt = 0; mt < 4; ++mt)
      #pragma unroll
      for (int nt = 0; nt < 4; ++nt)
        acc1[mt][nt] = MFMA16(fa[mt], fb[nt], acc1[mt][nt]);
  }
  // write back A now (featL dead since post-phase-1 barrier); own cols only.
  #pragma unroll
  for (int mt = 0; mt < 4; ++mt)
    #pragma unroll
    for (int nt = 0; nt < 2; ++nt) {
      int col = colw + nt * 16 + l15;
      #pragma unroll
      for (int r = 0; r < 4; ++r)
        Ab[(mt * 16 + quad * 4 + r) * LROW + col] = (__bf16)acc1[mt][nt][r];
    }

  // ---- phase 2 pass 2: D cols colw..colw+31 = h1 @ WdT (8 accs, live to ph5)
  f32x4 accD[4][2];
  {
    f32x4 zero = {0.f, 0.f, 0.f, 0.f};
    #pragma unroll
    for (int mt = 0; mt < 4; ++mt) { accD[mt][0] = zero; accD[mt][1] = zero; }
  }
  #pragma unroll
  for (int kb = 0; kb < 128; kb += 32) {
    const int ko = kb + quad * 8;
    bf16x8 fa[4], fd[2];
    #pragma unroll
    for (int mt = 0; mt < 4; ++mt)
      fa[mt] = *(const bf16x8*)&h1[(mt * 16 + l15) * LROW + ko];
    fd[0] = *(const bf16x8*)&WdT[(colw + l15) * 128 + ko];
    fd[1] = *(const bf16x8*)&WdT[(colw + 16 + l15) * 128 + ko];
    #pragma unroll
    for (int mt = 0; mt < 4; ++mt) {
      accD[mt][0] = MFMA16(fa[mt], fd[0], accD[mt][0]);
      accD[mt][1] = MFMA16(fa[mt], fd[1], accD[mt][1]);
    }
  }
  __syncthreads();   // h1 drain: all waves done reading Y before B overwrites it
  // write back B over the dead h1 region; own cols only -> NO barrier after.
  #pragma unroll
  for (int mt = 0; mt < 4; ++mt)
    #pragma unroll
    for (int nt = 2; nt < 4; ++nt) {
      int col = colw + (nt - 2) * 16 + l15;
      #pragma unroll
      for (int r = 0; r < 4; ++r)
        Bb[(mt * 16 + quad * 4 + r) * LROW + col] = (__bf16)acc1[mt][nt][r];
    }

  // ---- phase 4: edges, OWN-COLUMN mapping (no barrier since B write):
  //      wave w covers its cols colw..+31; quad -> graph pair; lane l15 ->
  //      adjacent col pair. S[i] = sum_{j!=i} relu(A[i]+B[j]+d_ij*w1d+cAB),
  //      written in place over A (same wave-owned cols).
  {
    const int c0 = colw + ((l15 & 8) << 1) + 2 * (l15 & 7);  // adjacent pair c0,c0+1
    const f32x2 wv = { vec[c0], vec[c0 + 1] };
    const f32x2 cv = { vec[128 + c0], vec[128 + c0 + 1] };
    const f32x2 z2 = {0.f, 0.f};
    #pragma unroll
    for (int gi = 0; gi < 2; ++gi) {
      const int g = 2 * quad + gi;
      f32x2 Bj[8];
      #pragma unroll
      for (int j = 0; j < 8; ++j) {
        unsigned vb = *(const unsigned*)&Bb[(g * 8 + j) * LROW + c0];
        Bj[j].x = bflo(vb); Bj[j].y = bfhi(vb);
      }
      #pragma unroll
      for (int i = 0; i < 8; ++i) {
        unsigned va = *(const unsigned*)&Ab[(g * 8 + i) * LROW + c0];
        f32x2 a = {bflo(va) + cv.x, bfhi(va) + cv.y};
        f32x2 s = z2;
        #pragma unroll
        for (int j = 0; j < 8; ++j) {
          if (j == i) continue;
          float d = dist[g * 64 + i * 8 + j];
          f32x2 d2 = {d, d};
          f32x2 t = __builtin_elementwise_fma(d2, wv, Bj[j]) + a;
          s += __builtin_elementwise_max(t, z2);
        }
        unsigned o = (unsigned)f2bf_u16(s.x) | ((unsigned)f2bf_u16(s.y) << 16);
        *(unsigned*)&Ab[(g * 8 + i) * LROW + c0] = o;   // in-place S
      }
    }
  }
  __syncthreads();   // S visible to all waves

  // ---- phase 5: ph = relu(S@Wc + D + cP); per-graph sum -> Sph (pad rows zeroed)
  {
    const __bf16* Sb = Ab;
    #pragma unroll
    for (int kb = 0; kb < 128; kb += 32) {
      const int ko = kb + quad * 8;
      bf16x8 fa[4], fc[2];
      #pragma unroll
      for (int mt = 0; mt < 4; ++mt)
        fa[mt] = *(const bf16x8*)&Sb[(mt * 16 + l15) * LROW + ko];
      fc[0] = *(const bf16x8*)&WcT[(colw + l15) * 128 + ko];
      fc[1] = *(const bf16x8*)&WcT[(colw + 16 + l15) * 128 + ko];
      #pragma unroll
      for (int mt = 0; mt < 4; ++mt) {
        accD[mt][0] = MFMA16(fa[mt], fc[0], accD[mt][0]);
        accD[mt][1] = MFMA16(fa[mt], fc[1], accD[mt][1]);
      }
    }
    #pragma unroll
    for (int mt = 0; mt < 4; ++mt)
      #pragma unroll
      for (int dt = 0; dt < 2; ++dt) {
        int col = colw + dt * 16 + l15;
        float cp = vec[256 + col];
        f32x4 a = accD[mt][dt];
        float s = fmaxf(a[0] + cp, 0.f) + fmaxf(a[1] + cp, 0.f)
                + fmaxf(a[2] + cp, 0.f) + fmaxf(a[3] + cp, 0.f);
        s += __shfl_xor(s, 16);
        int grow = mt * 2 + (lane >= 32 ? 1 : 0);
        if ((lane & 31) < 16) Sph[grow * LROW + col] = (__bf16)s;
        else                  Sph[(8 + grow) * LROW + col] = (__bf16)0.f;
      }
  }
  __syncthreads();

  // ---- phase 6: ho = relu(Sph @ WO + cO)  (M=16 tile: 8 graphs + 8 zero rows)
  {
    f32x4 acco[2];
    f32x4 zero = {0.f, 0.f, 0.f, 0.f};
    acco[0] = zero; acco[1] = zero;
    #pragma unroll
    for (int kb = 0; kb < 128; kb += 32) {
      const int ko = kb + quad * 8;
      bf16x8 fa = *(const bf16x8*)&Sph[l15 * LROW + ko];
      bf16x8 fb0 = *(const bf16x8*)&WoT[(colw + l15) * 128 + ko];
      bf16x8 fb1 = *(const bf16x8*)&WoT[(colw + 16 + l15) * 128 + ko];
      acco[0] = MFMA16(fa, fb0, acco[0]);
      acco[1] = MFMA16(fa, fb1, acco[1]);
    }
    #pragma unroll
    for (int dt = 0; dt < 2; ++dt) {
      int col = colw + dt * 16 + l15;
      float co = vec[384 + col];
      #pragma unroll
      for (int r = 0; r < 4; ++r)
        hob[(quad * 4 + r) * LROW + col] = (__bf16)fmaxf(acco[dt][r] + co, 0.f);
    }
  }
  __syncthreads();

  // ---- phase 7: logits = ho @ out_W2 + out_b2  (wave 0 only)
  if (w == 0) {
    f32x4 accf = {0.f, 0.f, 0.f, 0.f};
    #pragma unroll
    for (int kb = 0; kb < 128; kb += 32) {
      const int ko = kb + quad * 8;
      bf16x8 fa  = *(const bf16x8*)&hob[l15 * LROW + ko];
      bf16x8 fbv = *(const bf16x8*)&Wo2T[l15 * 128 + ko];
      accf = MFMA16(fa, fbv, accf);
    }
    if (quad < 2) {
      float b2 = out_b2[l15];
      #pragma unroll
      for (int r = 0; r < 4; ++r) {
        int row = quad * 4 + r;
        out[(g0 + row) * 16 + l15] = accf[r] + b2;
      }
    }
  }
}

extern "C" void kernel_launch(void* const* d_in, const int* in_sizes, int n_in,
                              void* d_out, int out_size, void* d_ws, size_t ws_size,
                              hipStream_t stream) {
  const int*   anchors   = (const int*)d_in[0];
  const int*   n_jumps   = (const int*)d_in[1];
  const float* positions = (const float*)d_in[2];
  const int*   colors    = (const int*)d_in[3];
  const int*   markers   = (const int*)d_in[4];
  const float* pre_W1  = (const float*)d_in[5];
  const float* pre_b1  = (const float*)d_in[6];
  const float* pre_W2  = (const float*)d_in[7];
  const float* pre_b2  = (const float*)d_in[8];
  const float* msg_W1  = (const float*)d_in[9];
  const float* msg_b1  = (const float*)d_in[10];
  const float* msg_W2  = (const float*)d_in[11];
  const float* msg_b2  = (const float*)d_in[12];
  const float* post_W1 = (const float*)d_in[13];
  const float* post_b1 = (const float*)d_in[14];
  const float* post_W2 = (const float*)d_in[15];
  const float* post_b2 = (const float*)d_in[16];
  const float* out_W1  = (const float*)d_in[17];
  const float* out_b1  = (const float*)d_in[18];
  const float* out_W2  = (const float*)d_in[19];
  const float* out_b2  = (const float*)d_in[20];

  char* ws = (char*)d_ws;
  unsigned short* WabT = (unsigned short*)(ws);            // [256][128] bf16
  unsigned short* WdT  = (unsigned short*)(ws + 65536);    // [128][128]
  unsigned short* WcT  = (unsigned short*)(ws + 98304);    // [128][128]
  unsigned short* WoT  = (unsigned short*)(ws + 131072);   // [128][128]
  unsigned short* Wo2T = (unsigned short*)(ws + 163840);   // [16][128]
  float*          vecs = (float*)(ws + 167936);            // 512 f32
  unsigned short* W1pT = (unsigned short*)(ws + 169984);   // [128][64] bf16

  const int BS = in_sizes[0];

  combine_weights<<<324, 256, 0, stream>>>(
      pre_W1, pre_b1, pre_W2, msg_W1, msg_W2, post_W1, post_W2, out_W1, out_W2,
      pre_b2, msg_b1, msg_b2, post_b1, post_b2, out_b1,
      WabT, WdT, WcT, WoT, Wo2T, W1pT, vecs);

  rrn_main<<<BS / 8, 256, 0, stream>>>(
      anchors, n_jumps, positions, colors, markers,
      (const __bf16*)W1pT,
      (const __bf16*)WabT, (const __bf16*)WdT, (const __bf16*)WcT,
      (const __bf16*)WoT, (const __bf16*)Wo2T, vecs, out_b2, (float*)d_out);
}

// Round 12
// 151.409 us; speedup vs baseline: 1.2141x; 1.0130x over previous
//
#include <hip/hip_runtime.h>

#define LROW 136   // padded LDS row stride in bf16 elements (128 + 8); 272 B rows
#define FSTR 72    // feat row stride in bf16 (64 K-cols + 8 pad); 144 B rows

typedef __bf16 bf16x8  __attribute__((ext_vector_type(8)));
typedef __bf16 bf16x2v __attribute__((ext_vector_type(2)));
typedef float  f32x4   __attribute__((ext_vector_type(4)));
typedef float  f32x2   __attribute__((ext_vector_type(2)));

#define MFMA16(a, b, c) __builtin_amdgcn_mfma_f32_16x16x32_bf16((a), (b), (c), 0, 0, 0)

__device__ __forceinline__ float bflo(unsigned v) { return __uint_as_float(v << 16); }
__device__ __forceinline__ float bfhi(unsigned v) { return __uint_as_float(v & 0xffff0000u); }

__device__ __forceinline__ unsigned short f2bf_u16(float f) {
  unsigned u = __float_as_uint(f);
  u += 0x7fffu + ((u >> 16) & 1u);
  return (unsigned short)(u >> 16);
}

// ---------------------------------------------------------------------------
// Kernel 1: fold linear layers into combined weight matrices (bf16, [n][k]
// transposed layout) + folded bias vectors (f32) + W1pT (pre_W1 transposed,
// bias folded as feature k=42, zero-padded to K=64). UNCHANGED from R11.
// ---------------------------------------------------------------------------
__global__ void combine_weights(
    const float* __restrict__ pre_W1, const float* __restrict__ pre_b1,
    const float* __restrict__ pre_W2, const float* __restrict__ msg_W1,
    const float* __restrict__ msg_W2, const float* __restrict__ post_W1,
    const float* __restrict__ post_W2, const float* __restrict__ out_W1,
    const float* __restrict__ out_W2, const float* __restrict__ pre_b2,
    const float* __restrict__ msg_b1, const float* __restrict__ msg_b2,
    const float* __restrict__ post_b1, const float* __restrict__ post_b2,
    const float* __restrict__ out_b1,
    unsigned short* __restrict__ WabT, unsigned short* __restrict__ WdT,
    unsigned short* __restrict__ WcT, unsigned short* __restrict__ WoT,
    unsigned short* __restrict__ Wo2T, unsigned short* __restrict__ W1pT,
    float* __restrict__ vecs)
{
  __shared__ float part[256];
  const int b = blockIdx.x;
  const int t = threadIdx.x;
  if (b < 320) {
    const int p  = b >> 6;
    const int kp = b & 63;
    const int k  = kp * 2 + (t >> 7);
    const int n  = t & 127;
    const float* L; const float* R; unsigned short* O;
    if (p == 0)      { L = pre_W2;  R = msg_W1;             O = WabT; }
    else if (p == 1) { L = pre_W2;  R = msg_W1 + 128*128;   O = WabT + 128*128; }
    else if (p == 2) { L = pre_W2;  R = post_W1 + 128*128;  O = WdT; }
    else if (p == 3) { L = msg_W2;  R = post_W1;            O = WcT; }
    else             { L = post_W2; R = out_W1;             O = WoT; }
    const float* Lr = L + k * 128;
    float a0 = 0.f, a1 = 0.f, a2 = 0.f, a3 = 0.f;
    #pragma unroll 8
    for (int m = 0; m < 128; m += 4) {
      a0 = fmaf(Lr[m + 0], R[(m + 0) * 128 + n], a0);
      a1 = fmaf(Lr[m + 1], R[(m + 1) * 128 + n], a1);
      a2 = fmaf(Lr[m + 2], R[(m + 2) * 128 + n], a2);
      a3 = fmaf(Lr[m + 3], R[(m + 3) * 128 + n], a3);
    }
    O[n * 128 + k] = f2bf_u16((a0 + a1) + (a2 + a3));
  } else if (b == 320) {
    // Wo2T transpose, w1d copy, W1pT build
    for (int idx = t; idx < 16 * 128; idx += 256) {
      int o = idx >> 7, k = idx & 127;
      Wo2T[o * 128 + k] = f2bf_u16(out_W2[k * 16 + o]);
    }
    if (t < 128) vecs[t] = msg_W1[256 * 128 + t];          // w1d
    for (int idx = t; idx < 128 * 64; idx += 256) {
      int n = idx >> 6, k = idx & 63;
      float v = (k < 42) ? pre_W1[k * 128 + n] : (k == 42 ? pre_b1[n] : 0.f);
      W1pT[n * 64 + k] = f2bf_u16(v);
    }
  } else {
    const int n = t & 127;
    const int h = t >> 7;
    float s = 0.f;
    if (b == 321) {            // cAB = pre_b2@(W1a+W1b) + msg_b1
      #pragma unroll 8
      for (int m = h * 64; m < h * 64 + 64; ++m)
        s = fmaf(pre_b2[m], msg_W1[m * 128 + n] + msg_W1[(128 + m) * 128 + n], s);
    } else if (b == 322) {     // cP = 7*msg_b2@P1a + pre_b2@P1b + post_b1
      #pragma unroll 8
      for (int m = h * 64; m < h * 64 + 64; ++m) {
        s = fmaf(7.f * msg_b2[m], post_W1[m * 128 + n], s);
        s = fmaf(pre_b2[m], post_W1[(128 + m) * 128 + n], s);
      }
    } else {                   // cO = 8*post_b2@out_W1 + out_b1
      #pragma unroll 8
      for (int m = h * 64; m < h * 64 + 64; ++m)
        s = fmaf(8.f * post_b2[m], out_W1[m * 128 + n], s);
    }
    part[t] = s;
    __syncthreads();
    if (t < 128) {
      float r = part[t] + part[t + 128];
      if (b == 321)      vecs[128 + t] = r + msg_b1[t];
      else if (b == 322) vecs[256 + t] = r + post_b1[t];
      else               vecs[384 + t] = r + out_b1[t];
    }
  }
}

// ---------------------------------------------------------------------------
// Kernel 2: fully fused RRN (R11 structure). R12: PAIRED-COLUMN epilogues --
// B-fragment lanes load weight rows (colw+2*l15, colw+2*l15+1) so each lane's
// two accumulators hold ADJACENT canonical columns; epilogues pack 2 bf16 ->
// one ds_write_b32. Halves LDS write-back instructions (the LDS pipe is the
// hypothesized serializer; VALU/barrier/occupancy moves were all neutral).
// LDS layouts, phase 4, phase 7, combine_weights unchanged.
// ---------------------------------------------------------------------------
__global__ void __launch_bounds__(256, 4) rrn_main(
    const int* __restrict__ anchors, const int* __restrict__ n_jumps,
    const float* __restrict__ positions, const int* __restrict__ colors,
    const int* __restrict__ markers,
    const __bf16* __restrict__ W1pT,
    const __bf16* __restrict__ WabT, const __bf16* __restrict__ WdT,
    const __bf16* __restrict__ WcT, const __bf16* __restrict__ WoT,
    const __bf16* __restrict__ Wo2T, const float* __restrict__ vecs,
    const float* __restrict__ out_b2, float* __restrict__ out)
{
  __shared__ __align__(16) char smem[38912];
  // X [0,17408): phases 0-1: featL bf16[64][FSTR]. Phase 2+: Ab (A, then S).
  // Y [17408,34816): h1 (phases 1-2); Bb after h1-drain; Sph @17408 /
  //   hob @21760 (phases 5+).  dist f32[512] @34816; vec f32[512] @36864.
  __bf16* featL = (__bf16*)(smem);
  __bf16* Ab    = (__bf16*)(smem);
  __bf16* h1    = (__bf16*)(smem + 17408);
  __bf16* Bb    = (__bf16*)(smem + 17408);
  __bf16* Sph   = (__bf16*)(smem + 17408);
  __bf16* hob   = (__bf16*)(smem + 21760);
  float*  dist  = (float*)(smem + 34816);
  float*  vec   = (float*)(smem + 36864);

  const int tid  = threadIdx.x;
  const int lane = tid & 63;
  const int w    = tid >> 6;      // wave 0..3
  const int l15  = lane & 15;
  const int quad = lane >> 4;
  const int colw = w * 32;        // this wave's 32-col slice
  const int crow = colw + 2 * l15; // paired-col base: lane owns cols crow, crow+1
  const int g0   = blockIdx.x * 8;
  const int n0   = blockIdx.x * 64;

  // ---- phase 0: build feature rows (thread-private: no race), dist, vec
  if (tid < 64) {
    uint4* rp = (uint4*)&featL[tid * FSTR];   // 144 B row, 16B-aligned
    uint4 z4 = {0u, 0u, 0u, 0u};
    #pragma unroll
    for (int i = 0; i < 9; ++i) rp[i] = z4;
    int g = tid >> 3;
    float px = positions[(n0 + tid) * 2], py = positions[(n0 + tid) * 2 + 1];
    int c  = colors[n0 + tid], mk = markers[n0 + tid] - 8;
    int a  = anchors[g0 + g],  nj = n_jumps[g0 + g];
    __bf16* row = &featL[tid * FSTR];
    row[0] = (__bf16)px; row[1] = (__bf16)py;
    const __bf16 one = (__bf16)1.f;
    row[2 + c] = one; row[10 + mk] = one;
    row[18 + a] = one; row[34 + nj] = one;
    row[42] = one;                              // bias-as-feature
  }
  for (int i = tid; i < 512; i += 256) {
    int g = i >> 6, ii = (i >> 3) & 7, jj = i & 7;
    const float* pa = positions + (n0 + g * 8 + ii) * 2;
    const float* pb = positions + (n0 + g * 8 + jj) * 2;
    float dx = pa[0] - pb[0], dy = pa[1] - pb[1];
    dist[i] = sqrtf(dx * dx + dy * dy);
  }
  for (int i = tid; i < 512; i += 256) vec[i] = vecs[i];
  __syncthreads();

  // ---- phase 1: h1 = relu(featL @ W1pT) via MFMA (M=64, N=128, K=64 padded).
  //      B-frag lanes load W1pT rows crow, crow+1 -> adjacent output cols.
  {
    f32x4 acch[4][2];
    f32x4 zero = {0.f, 0.f, 0.f, 0.f};
    #pragma unroll
    for (int mt = 0; mt < 4; ++mt) { acch[mt][0] = zero; acch[mt][1] = zero; }
    #pragma unroll
    for (int kb = 0; kb < 64; kb += 32) {
      const int ko = kb + quad * 8;
      bf16x8 fa[4], fb[2];
      #pragma unroll
      for (int mt = 0; mt < 4; ++mt)
        fa[mt] = *(const bf16x8*)&featL[(mt * 16 + l15) * FSTR + ko];
      fb[0] = *(const bf16x8*)&W1pT[(crow) * 64 + ko];
      fb[1] = *(const bf16x8*)&W1pT[(crow + 1) * 64 + ko];
      #pragma unroll
      for (int mt = 0; mt < 4; ++mt) {
        acch[mt][0] = MFMA16(fa[mt], fb[0], acch[mt][0]);
        acch[mt][1] = MFMA16(fa[mt], fb[1], acch[mt][1]);
      }
    }
    #pragma unroll
    for (int mt = 0; mt < 4; ++mt)
      #pragma unroll
      for (int r = 0; r < 4; ++r) {
        bf16x2v o = { (__bf16)fmaxf(acch[mt][0][r], 0.f),
                      (__bf16)fmaxf(acch[mt][1][r], 0.f) };
        *(bf16x2v*)&h1[(mt * 16 + quad * 4 + r) * LROW + crow] = o;
      }
  }
  __syncthreads();   // featL reads done + h1 visible

  // ---- phase 2 pass 1: [A|B] cols crow,crow+1 (x A,B halves) = h1 @ WabT
  f32x4 acc1[4][4];   // nt 0,1 -> A cols crow,crow+1; nt 2,3 -> B cols crow,crow+1
  {
    f32x4 zero = {0.f, 0.f, 0.f, 0.f};
    #pragma unroll
    for (int mt = 0; mt < 4; ++mt)
      #pragma unroll
      for (int nt = 0; nt < 4; ++nt) acc1[mt][nt] = zero;
  }
  #pragma unroll
  for (int kb = 0; kb < 128; kb += 32) {
    const int ko = kb + quad * 8;
    bf16x8 fa[4], fb[4];
    #pragma unroll
    for (int mt = 0; mt < 4; ++mt)
      fa[mt] = *(const bf16x8*)&h1[(mt * 16 + l15) * LROW + ko];
    fb[0] = *(const bf16x8*)&WabT[(crow) * 128 + ko];
    fb[1] = *(const bf16x8*)&WabT[(crow + 1) * 128 + ko];
    fb[2] = *(const bf16x8*)&WabT[(128 + crow) * 128 + ko];
    fb[3] = *(const bf16x8*)&WabT[(128 + crow + 1) * 128 + ko];
    #pragma unroll
    for (int mt = 0; mt < 4; ++mt)
      #pragma unroll
      for (int nt = 0; nt < 4; ++nt)
        acc1[mt][nt] = MFMA16(fa[mt], fb[nt], acc1[mt][nt]);
  }
  // write back A now (featL dead since post-phase-1 barrier); own cols only.
  #pragma unroll
  for (int mt = 0; mt < 4; ++mt)
    #pragma unroll
    for (int r = 0; r < 4; ++r) {
      bf16x2v o = { (__bf16)acc1[mt][0][r], (__bf16)acc1[mt][1][r] };
      *(bf16x2v*)&Ab[(mt * 16 + quad * 4 + r) * LROW + crow] = o;
    }

  // ---- phase 2 pass 2: D cols crow,crow+1 = h1 @ WdT (8 accs, live to ph5)
  f32x4 accD[4][2];
  {
    f32x4 zero = {0.f, 0.f, 0.f, 0.f};
    #pragma unroll
    for (int mt = 0; mt < 4; ++mt) { accD[mt][0] = zero; accD[mt][1] = zero; }
  }
  #pragma unroll
  for (int kb = 0; kb < 128; kb += 32) {
    const int ko = kb + quad * 8;
    bf16x8 fa[4], fd[2];
    #pragma unroll
    for (int mt = 0; mt < 4; ++mt)
      fa[mt] = *(const bf16x8*)&h1[(mt * 16 + l15) * LROW + ko];
    fd[0] = *(const bf16x8*)&WdT[(crow) * 128 + ko];
    fd[1] = *(const bf16x8*)&WdT[(crow + 1) * 128 + ko];
    #pragma unroll
    for (int mt = 0; mt < 4; ++mt) {
      accD[mt][0] = MFMA16(fa[mt], fd[0], accD[mt][0]);
      accD[mt][1] = MFMA16(fa[mt], fd[1], accD[mt][1]);
    }
  }
  __syncthreads();   // h1 drain: all waves done reading Y before B overwrites it
  // write back B over the dead h1 region; own cols only -> NO barrier after.
  #pragma unroll
  for (int mt = 0; mt < 4; ++mt)
    #pragma unroll
    for (int r = 0; r < 4; ++r) {
      bf16x2v o = { (__bf16)acc1[mt][2][r], (__bf16)acc1[mt][3][r] };
      *(bf16x2v*)&Bb[(mt * 16 + quad * 4 + r) * LROW + crow] = o;
    }

  // ---- phase 4: edges, OWN-COLUMN mapping (no barrier since B write):
  //      wave w covers its cols colw..+31; quad -> graph pair; lane l15 ->
  //      adjacent col pair. S[i] = sum_{j!=i} relu(A[i]+B[j]+d_ij*w1d+cAB),
  //      written in place over A (same wave-owned cols). UNCHANGED from R11.
  {
    const int c0 = colw + ((l15 & 8) << 1) + 2 * (l15 & 7);  // adjacent pair c0,c0+1
    const f32x2 wv = { vec[c0], vec[c0 + 1] };
    const f32x2 cv = { vec[128 + c0], vec[128 + c0 + 1] };
    const f32x2 z2 = {0.f, 0.f};
    #pragma unroll
    for (int gi = 0; gi < 2; ++gi) {
      const int g = 2 * quad + gi;
      f32x2 Bj[8];
      #pragma unroll
      for (int j = 0; j < 8; ++j) {
        unsigned vb = *(const unsigned*)&Bb[(g * 8 + j) * LROW + c0];
        Bj[j].x = bflo(vb); Bj[j].y = bfhi(vb);
      }
      #pragma unroll
      for (int i = 0; i < 8; ++i) {
        unsigned va = *(const unsigned*)&Ab[(g * 8 + i) * LROW + c0];
        f32x2 a = {bflo(va) + cv.x, bfhi(va) + cv.y};
        f32x2 s = z2;
        #pragma unroll
        for (int j = 0; j < 8; ++j) {
          if (j == i) continue;
          float d = dist[g * 64 + i * 8 + j];
          f32x2 d2 = {d, d};
          f32x2 t = __builtin_elementwise_fma(d2, wv, Bj[j]) + a;
          s += __builtin_elementwise_max(t, z2);
        }
        unsigned o = (unsigned)f2bf_u16(s.x) | ((unsigned)f2bf_u16(s.y) << 16);
        *(unsigned*)&Ab[(g * 8 + i) * LROW + c0] = o;   // in-place S
      }
    }
  }
  __syncthreads();   // S visible to all waves

  // ---- phase 5: ph = relu(S@Wc + D + cP); per-graph sum -> Sph (pad rows
  //      zeroed). fc rows crow,crow+1 match accD's col assignment.
  {
    const __bf16* Sb = Ab;
    #pragma unroll
    for (int kb = 0; kb < 128; kb += 32) {
      const int ko = kb + quad * 8;
      bf16x8 fa[4], fc[2];
      #pragma unroll
      for (int mt = 0; mt < 4; ++mt)
        fa[mt] = *(const bf16x8*)&Sb[(mt * 16 + l15) * LROW + ko];
      fc[0] = *(const bf16x8*)&WcT[(crow) * 128 + ko];
      fc[1] = *(const bf16x8*)&WcT[(crow + 1) * 128 + ko];
      #pragma unroll
      for (int mt = 0; mt < 4; ++mt) {
        accD[mt][0] = MFMA16(fa[mt], fc[0], accD[mt][0]);
        accD[mt][1] = MFMA16(fa[mt], fc[1], accD[mt][1]);
      }
    }
    const f32x2 cpv = *(const f32x2*)&vec[256 + crow];
    #pragma unroll
    for (int mt = 0; mt < 4; ++mt) {
      f32x4 a0 = accD[mt][0];
      f32x4 a1 = accD[mt][1];
      float s0 = fmaxf(a0[0] + cpv.x, 0.f) + fmaxf(a0[1] + cpv.x, 0.f)
               + fmaxf(a0[2] + cpv.x, 0.f) + fmaxf(a0[3] + cpv.x, 0.f);
      float s1 = fmaxf(a1[0] + cpv.y, 0.f) + fmaxf(a1[1] + cpv.y, 0.f)
               + fmaxf(a1[2] + cpv.y, 0.f) + fmaxf(a1[3] + cpv.y, 0.f);
      s0 += __shfl_xor(s0, 16);
      s1 += __shfl_xor(s1, 16);
      int grow = mt * 2 + (lane >= 32 ? 1 : 0);
      if ((lane & 31) < 16) {
        bf16x2v o = { (__bf16)s0, (__bf16)s1 };
        *(bf16x2v*)&Sph[grow * LROW + crow] = o;
      } else {
        *(unsigned*)&Sph[(8 + grow) * LROW + crow] = 0u;  // zero pad rows
      }
    }
  }
  __syncthreads();

  // ---- phase 6: ho = relu(Sph @ WO + cO)  (M=16 tile: 8 graphs + 8 zero rows)
  {
    f32x4 acco[2];
    f32x4 zero = {0.f, 0.f, 0.f, 0.f};
    acco[0] = zero; acco[1] = zero;
    #pragma unroll
    for (int kb = 0; kb < 128; kb += 32) {
      const int ko = kb + quad * 8;
      bf16x8 fa = *(const bf16x8*)&Sph[l15 * LROW + ko];
      bf16x8 fb0 = *(const bf16x8*)&WoT[(crow) * 128 + ko];
      bf16x8 fb1 = *(const bf16x8*)&WoT[(crow + 1) * 128 + ko];
      acco[0] = MFMA16(fa, fb0, acco[0]);
      acco[1] = MFMA16(fa, fb1, acco[1]);
    }
    const f32x2 cov = *(const f32x2*)&vec[384 + crow];
    #pragma unroll
    for (int r = 0; r < 4; ++r) {
      bf16x2v o = { (__bf16)fmaxf(acco[0][r] + cov.x, 0.f),
                    (__bf16)fmaxf(acco[1][r] + cov.y, 0.f) };
      *(bf16x2v*)&hob[(quad * 4 + r) * LROW + crow] = o;
    }
  }
  __syncthreads();

  // ---- phase 7: logits = ho @ out_W2 + out_b2  (wave 0 only) UNCHANGED
  if (w == 0) {
    f32x4 accf = {0.f, 0.f, 0.f, 0.f};
    #pragma unroll
    for (int kb = 0; kb < 128; kb += 32) {
      const int ko = kb + quad * 8;
      bf16x8 fa  = *(const bf16x8*)&hob[l15 * LROW + ko];
      bf16x8 fbv = *(const bf16x8*)&Wo2T[l15 * 128 + ko];
      accf = MFMA16(fa, fbv, accf);
    }
    if (quad < 2) {
      float b2 = out_b2[l15];
      #pragma unroll
      for (int r = 0; r < 4; ++r) {
        int row = quad * 4 + r;
        out[(g0 + row) * 16 + l15] = accf[r] + b2;
      }
    }
  }
}

extern "C" void kernel_launch(void* const* d_in, const int* in_sizes, int n_in,
                              void* d_out, int out_size, void* d_ws, size_t ws_size,
                              hipStream_t stream) {
  const int*   anchors   = (const int*)d_in[0];
  const int*   n_jumps   = (const int*)d_in[1];
  const float* positions = (const float*)d_in[2];
  const int*   colors    = (const int*)d_in[3];
  const int*   markers   = (const int*)d_in[4];
  const float* pre_W1  = (const float*)d_in[5];
  const float* pre_b1  = (const float*)d_in[6];
  const float* pre_W2  = (const float*)d_in[7];
  const float* pre_b2  = (const float*)d_in[8];
  const float* msg_W1  = (const float*)d_in[9];
  const float* msg_b1  = (const float*)d_in[10];
  const float* msg_W2  = (const float*)d_in[11];
  const float* msg_b2  = (const float*)d_in[12];
  const float* post_W1 = (const float*)d_in[13];
  const float* post_b1 = (const float*)d_in[14];
  const float* post_W2 = (const float*)d_in[15];
  const float* post_b2 = (const float*)d_in[16];
  const float* out_W1  = (const float*)d_in[17];
  const float* out_b1  = (const float*)d_in[18];
  const float* out_W2  = (const float*)d_in[19];
  const float* out_b2  = (const float*)d_in[20];

  char* ws = (char*)d_ws;
  unsigned short* WabT = (unsigned short*)(ws);            // [256][128] bf16
  unsigned short* WdT  = (unsigned short*)(ws + 65536);    // [128][128]
  unsigned short* WcT  = (unsigned short*)(ws + 98304);    // [128][128]
  unsigned short* WoT  = (unsigned short*)(ws + 131072);   // [128][128]
  unsigned short* Wo2T = (unsigned short*)(ws + 163840);   // [16][128]
  float*          vecs = (float*)(ws + 167936);            // 512 f32
  unsigned short* W1pT = (unsigned short*)(ws + 169984);   // [128][64] bf16

  const int BS = in_sizes[0];

  combine_weights<<<324, 256, 0, stream>>>(
      pre_W1, pre_b1, pre_W2, msg_W1, msg_W2, post_W1, post_W2, out_W1, out_W2,
      pre_b2, msg_b1, msg_b2, post_b1, post_b2, out_b1,
      WabT, WdT, WcT, WoT, Wo2T, W1pT, vecs);

  rrn_main<<<BS / 8, 256, 0, stream>>>(
      anchors, n_jumps, positions, colors, markers,
      (const __bf16*)W1pT,
      (const __bf16*)WabT, (const __bf16*)WdT, (const __bf16*)WcT,
      (const __bf16*)WoT, (const __bf16*)Wo2T, vecs, out_b2, (float*)d_out);
}